// Round 2
// baseline (294.898 us; speedup 1.0000x reference)
//
#include <hip/hip_runtime.h>

#define B_  8
#define C_  128
#define H_  128
#define W_  256
#define HW_ (H_ * W_)
#define TH  16
#define TW  32
#define S2R 24            // f2 tile rows  = TH + 8
#define S2C 40            // f2 tile cols (dwords, each dword = 2 channels f16)
#define S2S 44            // padded f2 row stride (dwords)
#define S1S 36            // padded f1 row stride (dwords)
#define S1OFF (S2R * S2S) // 1056
#define LDSN  (S1OFF + TH * S1S) // 1632 dwords per buffer
#define NTHREADS 576

typedef __fp16 h2 __attribute__((ext_vector_type(2)));

__device__ __forceinline__ float dot2f16(unsigned int a, unsigned int b, float c) {
#if __has_builtin(__builtin_amdgcn_fdot2)
    return __builtin_amdgcn_fdot2(__builtin_bit_cast(h2, a),
                                  __builtin_bit_cast(h2, b), c, false);
#else
    h2 ha = __builtin_bit_cast(h2, a), hb = __builtin_bit_cast(h2, b);
    return c + (float)ha.x * (float)hb.x + (float)ha.y * (float)hb.y;
#endif
}

__device__ __forceinline__ unsigned int pk(float x, float y) {
    h2 r = __builtin_amdgcn_cvt_pkrtz(x, y);
    return __builtin_bit_cast(unsigned int, r);
}

__global__ __launch_bounds__(NTHREADS, 4) void cv_kernel(
    const float* __restrict__ f1g, const float* __restrict__ f2g,
    float* __restrict__ outg) {
    __shared__ __align__(16) unsigned int lds[2][LDSN];

    const int tid = threadIdx.x;
    const int w0 = blockIdx.x * TW;
    const int h0 = blockIdx.y * TH;
    const int b  = blockIdx.z;

    // ---- staging slot setup (slot0: all threads; slot1: tid < 160) ----
    // Each slot stages 2 consecutive pixels x 2 channels (two dwordx2 global
    // loads at off and off+HW) packed into 2 LDS dwords of {f16(c),f16(c+1)}.
    int off0, off1 = 0, ld0, ld1 = 0;
    float m0;
    const float* p0;
    const float* p1 = f1g;
    if (tid < 480) {                       // f2 tile: 24 rows x 20 pairs
        int r  = tid / 20, cc = (tid % 20) * 2;
        int gh = h0 - 4 + r, gw = w0 - 4 + cc;
        bool valid = (gh >= 0) && (gh < H_) && (gw >= 0) && (gw + 1 < W_);
        int ghc = min(max(gh, 0), H_ - 1);
        int gwc = min(max(gw, 0), W_ - 2);
        off0 = (b * C_ * H_ + ghc) * W_ + gwc;
        p0   = f2g;
        ld0  = r * S2S + cc;
        m0   = valid ? 1.f : 0.f;
    } else {                               // f1 tile rows 0..5
        int t = tid - 480;
        int r = t / 16, cc = (t % 16) * 2;
        off0 = (b * C_ * H_ + h0 + r) * W_ + w0 + cc;
        p0   = f1g;
        ld0  = S1OFF + r * S1S + cc;
        m0   = 1.f;
    }
    if (tid < 160) {                       // f1 tile rows 6..15
        int t = 96 + tid;
        int r = t / 16, cc = (t % 16) * 2;
        off1 = (b * C_ * H_ + h0 + r) * W_ + w0 + cc;
        ld1  = S1OFF + r * S1S + cc;
    }

    // ---- prologue: stage channels {0,1} into buffer 0 ----
    {
        float2 A = *(const float2*)(p0 + off0);
        float2 Bv = *(const float2*)(p0 + off0 + HW_);
        lds[0][ld0]     = pk(A.x * m0, Bv.x * m0);
        lds[0][ld0 + 1] = pk(A.y * m0, Bv.y * m0);
        if (tid < 160) {
            float2 A1 = *(const float2*)(p1 + off1);
            float2 B1 = *(const float2*)(p1 + off1 + HW_);
            lds[0][ld1]     = pk(A1.x, B1.x);
            lds[0][ld1 + 1] = pk(A1.y, B1.y);
        }
    }
    __syncthreads();

    // ---- compute mapping: wave = di, lane -> (row hh, 8-wide strip ww) ----
    const int di   = tid >> 6;
    const int lane = tid & 63;
    const int hh   = lane >> 2;
    const int sc   = lane & 3;
    const int ww   = sc * 8;
    const int rdF2 = (hh + di) * S2S + ww;       // 16B aligned
    const int rdF1 = S1OFF + hh * S1S + ww;      // 16B aligned

    float acc[9][8];
#pragma unroll
    for (int j = 0; j < 9; ++j)
#pragma unroll
        for (int p = 0; p < 8; ++p) acc[j][p] = 0.f;

#pragma unroll 2
    for (int it = 0; it < 64; ++it) {
        unsigned int* cur = lds[it & 1];
        unsigned int* nxt = lds[(it & 1) ^ 1];
        const bool more = (it < 63);

        // prefetch next channel pair (latency hidden under the dot2 block)
        float2 A0, B0, A1, B1;
        if (more) {
            off0 += 2 * HW_;
            A0 = *(const float2*)(p0 + off0);
            B0 = *(const float2*)(p0 + off0 + HW_);
            if (tid < 160) {
                off1 += 2 * HW_;
                A1 = *(const float2*)(p1 + off1);
                B1 = *(const float2*)(p1 + off1 + HW_);
            }
        }

        // LDS -> regs: 4x b128 (f2 row segment, 16 dwords) + 2x b128 (f1 strip)
        uint4 fa = *(const uint4*)(cur + rdF2);
        uint4 fb = *(const uint4*)(cur + rdF2 + 4);
        uint4 fc = *(const uint4*)(cur + rdF2 + 8);
        uint4 fd = *(const uint4*)(cur + rdF2 + 12);
        uint4 ga = *(const uint4*)(cur + rdF1);
        uint4 gb = *(const uint4*)(cur + rdF1 + 4);

        unsigned int f2u[16] = {fa.x, fa.y, fa.z, fa.w, fb.x, fb.y, fb.z, fb.w,
                                fc.x, fc.y, fc.z, fc.w, fd.x, fd.y, fd.z, fd.w};
        unsigned int f1u[8]  = {ga.x, ga.y, ga.z, ga.w, gb.x, gb.y, gb.z, gb.w};

#pragma unroll
        for (int j = 0; j < 9; ++j)
#pragma unroll
            for (int p = 0; p < 8; ++p)
                acc[j][p] = dot2f16(f1u[p], f2u[p + j], acc[j][p]);

        // write staged next pair into the other buffer
        if (more) {
            nxt[ld0]     = pk(A0.x * m0, B0.x * m0);
            nxt[ld0 + 1] = pk(A0.y * m0, B0.y * m0);
            if (tid < 160) {
                nxt[ld1]     = pk(A1.x, B1.x);
                nxt[ld1 + 1] = pk(A1.y, B1.y);
            }
        }
        __syncthreads();
    }

    // ---- epilogue: mean over C and store ----
    const float inv = 1.0f / 128.0f;
    int obase = ((b * 81 + di * 9) * H_ + h0 + hh) * W_ + w0 + ww;
#pragma unroll
    for (int j = 0; j < 9; ++j) {
        float4 o0 = make_float4(acc[j][0] * inv, acc[j][1] * inv,
                                acc[j][2] * inv, acc[j][3] * inv);
        float4 o1 = make_float4(acc[j][4] * inv, acc[j][5] * inv,
                                acc[j][6] * inv, acc[j][7] * inv);
        *(float4*)(outg + obase)     = o0;
        *(float4*)(outg + obase + 4) = o1;
        obase += HW_;
    }
}

extern "C" void kernel_launch(void* const* d_in, const int* in_sizes, int n_in,
                              void* d_out, int out_size, void* d_ws, size_t ws_size,
                              hipStream_t stream) {
    const float* f1 = (const float*)d_in[0];
    const float* f2 = (const float*)d_in[1];
    float* out = (float*)d_out;
    dim3 grid(W_ / TW, H_ / TH, B_);   // 8 x 8 x 8 = 512 blocks
    cv_kernel<<<grid, NTHREADS, 0, stream>>>(f1, f2, out);
}

// Round 3
// 146.074 us; speedup vs baseline: 2.0188x; 2.0188x over previous
//
#include <hip/hip_runtime.h>

#define B_  8
#define C_  128
#define H_  128
#define W_  256
#define HW_ (H_ * W_)
#define TH  16
#define TW  32
#define S2S 44                 // padded f2 row stride (dwords)
#define S1S 36                 // padded f1 row stride (dwords)
#define S1OFF (24 * S2S)       // 1056 (f2 tile = 24 rows)
#define PAIRN (S1OFF + TH * S1S) // 1632 dwords per channel-pair tile
#define NTHREADS 576

typedef __fp16 h2 __attribute__((ext_vector_type(2)));

__device__ __forceinline__ float dot2f16(unsigned int a, unsigned int b, float c) {
#if __has_builtin(__builtin_amdgcn_fdot2)
    return __builtin_amdgcn_fdot2(__builtin_bit_cast(h2, a),
                                  __builtin_bit_cast(h2, b), c, false);
#else
    h2 ha = __builtin_bit_cast(h2, a), hb = __builtin_bit_cast(h2, b);
    return c + (float)ha.x * (float)hb.x + (float)ha.y * (float)hb.y;
#endif
}

__device__ __forceinline__ unsigned int pk(float x, float y) {
    h2 r = __builtin_amdgcn_cvt_pkrtz(x, y);
    return __builtin_bit_cast(unsigned int, r);
}

// 9-wave block: wave = di (0..8); lane -> (row hh 0..15, 8-px strip sc 0..3).
// LDS holds 2 buffers x 2 channel-pairs of {f2 24x44, f1 16x36} packed f16x2.
// Each stage: prefetch 4 channels for stage+1, compute 2 pairs (144 dot2/lane),
// write staged, barrier. 32 stages total.
__global__ __launch_bounds__(NTHREADS, 3) void cv_kernel(
    const float* __restrict__ f1g, const float* __restrict__ f2g,
    float* __restrict__ outg) {
    __shared__ __align__(16) unsigned int lds[2][2][PAIRN];

    const int tid = threadIdx.x;
    const int w0 = blockIdx.x * TW;
    const int h0 = blockIdx.y * TH;
    const int b  = blockIdx.z;

    // ---- staging slot setup (slot0: all threads; slot1: tid < 160) ----
    int off0, off1 = 0, ld0, ld1 = 0;
    float m0;
    const float* p0;
    const float* p1 = f1g;
    if (tid < 480) {                       // f2 tile: 24 rows x 20 pairs
        int r  = tid / 20, cc = (tid % 20) * 2;
        int gh = h0 - 4 + r, gw = w0 - 4 + cc;
        bool valid = (gh >= 0) && (gh < H_) && (gw >= 0) && (gw + 1 < W_);
        int ghc = min(max(gh, 0), H_ - 1);
        int gwc = min(max(gw, 0), W_ - 2);
        off0 = (b * C_ * H_ + ghc) * W_ + gwc;
        p0   = f2g;
        ld0  = r * S2S + cc;
        m0   = valid ? 1.f : 0.f;
    } else {                               // f1 tile rows 0..5
        int t = tid - 480;
        int r = t / 16, cc = (t % 16) * 2;
        off0 = (b * C_ * H_ + h0 + r) * W_ + w0 + cc;
        p0   = f1g;
        ld0  = S1OFF + r * S1S + cc;
        m0   = 1.f;
    }
    if (tid < 160) {                       // f1 tile rows 6..15
        int t = 96 + tid;
        int r = t / 16, cc = (t % 16) * 2;
        off1 = (b * C_ * H_ + h0 + r) * W_ + w0 + cc;
        ld1  = S1OFF + r * S1S + cc;
    }

    // ---- prologue: stage channels {0,1,2,3} into buffer 0 ----
    {
        float2 A0 = *(const float2*)(p0 + off0);
        float2 B0 = *(const float2*)(p0 + off0 + HW_);
        float2 A1 = *(const float2*)(p0 + off0 + 2 * HW_);
        float2 B1 = *(const float2*)(p0 + off0 + 3 * HW_);
        lds[0][0][ld0]     = pk(A0.x * m0, B0.x * m0);
        lds[0][0][ld0 + 1] = pk(A0.y * m0, B0.y * m0);
        lds[0][1][ld0]     = pk(A1.x * m0, B1.x * m0);
        lds[0][1][ld0 + 1] = pk(A1.y * m0, B1.y * m0);
        if (tid < 160) {
            float2 C0 = *(const float2*)(p1 + off1);
            float2 D0 = *(const float2*)(p1 + off1 + HW_);
            float2 C1 = *(const float2*)(p1 + off1 + 2 * HW_);
            float2 D1 = *(const float2*)(p1 + off1 + 3 * HW_);
            lds[0][0][ld1]     = pk(C0.x, D0.x);
            lds[0][0][ld1 + 1] = pk(C0.y, D0.y);
            lds[0][1][ld1]     = pk(C1.x, D1.x);
            lds[0][1][ld1 + 1] = pk(C1.y, D1.y);
        }
    }
    __syncthreads();

    // ---- compute mapping ----
    const int di   = tid >> 6;
    const int lane = tid & 63;
    const int hh   = lane >> 2;
    const int sc   = lane & 3;
    const int ww   = sc * 8;
    const int rdF2 = (hh + di) * S2S + ww;       // 16B aligned
    const int rdF1 = S1OFF + hh * S1S + ww;      // 16B aligned

    float acc[9][8];
#pragma unroll
    for (int j = 0; j < 9; ++j)
#pragma unroll
        for (int p = 0; p < 8; ++p) acc[j][p] = 0.f;

    for (int it = 0; it < 32; ++it) {
        unsigned int (*cur)[PAIRN] = lds[it & 1];
        unsigned int (*nxt)[PAIRN] = lds[(it & 1) ^ 1];
        const bool more = (it < 31);

        // prefetch next 4 channels (in flight across the dot2 block)
        float2 A0, B0, A1, B1, C0, D0, C1, D1;
        if (more) {
            off0 += 4 * HW_;
            A0 = *(const float2*)(p0 + off0);
            B0 = *(const float2*)(p0 + off0 + HW_);
            A1 = *(const float2*)(p0 + off0 + 2 * HW_);
            B1 = *(const float2*)(p0 + off0 + 3 * HW_);
            if (tid < 160) {
                off1 += 4 * HW_;
                C0 = *(const float2*)(p1 + off1);
                D0 = *(const float2*)(p1 + off1 + HW_);
                C1 = *(const float2*)(p1 + off1 + 2 * HW_);
                D1 = *(const float2*)(p1 + off1 + 3 * HW_);
            }
        }

#pragma unroll
        for (int q = 0; q < 2; ++q) {
            const unsigned int* buf = cur[q];
            uint4 fa = *(const uint4*)(buf + rdF2);
            uint4 fb = *(const uint4*)(buf + rdF2 + 4);
            uint4 fc = *(const uint4*)(buf + rdF2 + 8);
            uint4 fd = *(const uint4*)(buf + rdF2 + 12);
            uint4 ga = *(const uint4*)(buf + rdF1);
            uint4 gb = *(const uint4*)(buf + rdF1 + 4);

            unsigned int f2u[16] = {fa.x, fa.y, fa.z, fa.w, fb.x, fb.y, fb.z, fb.w,
                                    fc.x, fc.y, fc.z, fc.w, fd.x, fd.y, fd.z, fd.w};
            unsigned int f1u[8]  = {ga.x, ga.y, ga.z, ga.w, gb.x, gb.y, gb.z, gb.w};

#pragma unroll
            for (int j = 0; j < 9; ++j)
#pragma unroll
                for (int p = 0; p < 8; ++p)
                    acc[j][p] = dot2f16(f1u[p], f2u[p + j], acc[j][p]);
        }

        // write staged next 4 channels into the other buffer
        if (more) {
            nxt[0][ld0]     = pk(A0.x * m0, B0.x * m0);
            nxt[0][ld0 + 1] = pk(A0.y * m0, B0.y * m0);
            nxt[1][ld0]     = pk(A1.x * m0, B1.x * m0);
            nxt[1][ld0 + 1] = pk(A1.y * m0, B1.y * m0);
            if (tid < 160) {
                nxt[0][ld1]     = pk(C0.x, D0.x);
                nxt[0][ld1 + 1] = pk(C0.y, D0.y);
                nxt[1][ld1]     = pk(C1.x, D1.x);
                nxt[1][ld1 + 1] = pk(C1.y, D1.y);
            }
        }
        __syncthreads();
    }

    // ---- epilogue: mean over C and store ----
    const float inv = 1.0f / 128.0f;
    int obase = ((b * 81 + di * 9) * H_ + h0 + hh) * W_ + w0 + ww;
#pragma unroll
    for (int j = 0; j < 9; ++j) {
        float4 o0 = make_float4(acc[j][0] * inv, acc[j][1] * inv,
                                acc[j][2] * inv, acc[j][3] * inv);
        float4 o1 = make_float4(acc[j][4] * inv, acc[j][5] * inv,
                                acc[j][6] * inv, acc[j][7] * inv);
        *(float4*)(outg + obase)     = o0;
        *(float4*)(outg + obase + 4) = o1;
        obase += HW_;
    }
}

extern "C" void kernel_launch(void* const* d_in, const int* in_sizes, int n_in,
                              void* d_out, int out_size, void* d_ws, size_t ws_size,
                              hipStream_t stream) {
    const float* f1 = (const float*)d_in[0];
    const float* f2 = (const float*)d_in[1];
    float* out = (float*)d_out;
    dim3 grid(W_ / TW, H_ / TH, B_);   // 8 x 8 x 8 = 512 blocks
    cv_kernel<<<grid, NTHREADS, 0, stream>>>(f1, f2, out);
}